// Round 1
// baseline (268.763 us; speedup 1.0000x reference)
//
#include <hip/hip_runtime.h>
#include <cstdint>
#include <cstddef>

#define B_  8
#define S_  1024
#define D_  1024
#define H_  8
#define HD_ 128
#define N3_ 3072
#define PREFIX 77
#define MASKED_BIAS -10000.0f

typedef __bf16 bf16x8 __attribute__((ext_vector_type(8)));
typedef float  f32x4  __attribute__((ext_vector_type(4)));

__device__ __forceinline__ unsigned short f2bf_rne(float f) {
    unsigned int u = __float_as_uint(f);
    u += 0x7FFFu + ((u >> 16) & 1u);
    return (unsigned short)(u >> 16);
}
__device__ __forceinline__ float bf2f(unsigned short h) {
    return __uint_as_float(((unsigned int)h) << 16);
}

// async 16B global->LDS. ldsptr must be WAVE-UNIFORM; HW deposits at base + lane*16.
__device__ __forceinline__ void load_lds16(const unsigned short* g, unsigned short* l) {
    __builtin_amdgcn_global_load_lds(
        (const __attribute__((address_space(1))) unsigned int*)g,
        (__attribute__((address_space(3))) unsigned int*)l,
        16, 0, 0);
}

// ---------------- prep kernels ----------------

__global__ void cvt_bf16(const float* __restrict__ in, unsigned short* __restrict__ out, int n4) {
    int i = blockIdx.x * blockDim.x + threadIdx.x;
    if (i >= n4) return;
    float4 v = reinterpret_cast<const float4*>(in)[i];
    ushort4 o;
    o.x = f2bf_rne(v.x); o.y = f2bf_rne(v.y); o.z = f2bf_rne(v.z); o.w = f2bf_rne(v.w);
    reinterpret_cast<ushort4*>(out)[i] = o;
}

// in fp32 [R][C] -> out bf16 [C][R]
__global__ void transpose_cvt(const float* __restrict__ in, unsigned short* __restrict__ out,
                              int R, int C) {
    __shared__ float tile[32][33];
    const int c0 = blockIdx.x * 32, r0 = blockIdx.y * 32;
    const int tx = threadIdx.x, ty = threadIdx.y;
    #pragma unroll
    for (int i = 0; i < 4; ++i)
        tile[ty + i * 8][tx] = in[(size_t)(r0 + ty + i * 8) * C + c0 + tx];
    __syncthreads();
    #pragma unroll
    for (int i = 0; i < 4; ++i)
        out[(size_t)(c0 + ty + i * 8) * R + r0 + tx] = f2bf_rne(tile[tx][ty + i * 8]);
}

// V bf16 [bh][s][128] -> Vt bf16 [bh][128][s]
__global__ void transpose_v(const unsigned short* __restrict__ v, unsigned short* __restrict__ vt) {
    __shared__ unsigned short tile[32][33];
    const int bh = blockIdx.z;
    const int d0 = blockIdx.x * 32, s0 = blockIdx.y * 32;
    const unsigned short* vi = v + (size_t)bh * S_ * HD_;
    unsigned short* vo = vt + (size_t)bh * S_ * HD_;
    const int tx = threadIdx.x, ty = threadIdx.y;
    #pragma unroll
    for (int i = 0; i < 4; ++i)
        tile[ty + i * 8][tx] = vi[(size_t)(s0 + ty + i * 8) * HD_ + d0 + tx];
    __syncthreads();
    #pragma unroll
    for (int i = 0; i < 4; ++i)
        vo[(size_t)(d0 + ty + i * 8) * S_ + s0 + tx] = tile[tx][ty + i * 8];
}

// ---------------- pipelined GEMM core (R7) ----------------
// 256x128 tile, BK=32, 512 threads = 8 waves (4M x 2N, 64x64 per wave).
// LDS ring of 5 stages (120 KB), stage lead = 3 K-steps, ONE raw s_barrier per
// K-step, counted vmcnt(9) (never 0 in main loop). Safety:
//  - clobber: stage(t+3) writes buf[(t-2)%5]; its last reader finished before
//    barrier(t-1), and the issue is after that barrier in every wave -> safe.
//  - visibility: all waves issue the identical 3-load/step sequence, so
//    vmcnt(9) (= newest 3 stages outstanding) + barrier proves stage(t) landed
//    block-wide before any ds_read of it.
// LDS XOR-swizzle (T2): read chunk ^= (row>>1)&3 (validated against the 6.3M
// SQ_LDS_BANK_CONFLICT = 4 cy/read of the unswizzled layout); staging uses the
// inverse-swizzled GLOBAL source with a linear LDS dest (rule 21).
// Accumulation order over k identical to R6 -> bitwise-same outputs.

#define QK_ASTR (256 * 32)
#define QK_BSTR (128 * 32)

__global__ __launch_bounds__(512, 2) void gemm_qkv(
    const unsigned short* __restrict__ xb,
    const unsigned short* __restrict__ wt,
    const float* __restrict__ bias,
    unsigned short* __restrict__ qb,
    unsigned short* __restrict__ kb,
    unsigned short* __restrict__ vb) {
    __shared__ unsigned short As[5 * QK_ASTR];   // 80 KB
    __shared__ unsigned short Bs[5 * QK_BSTR];   // 40 KB
    const int tid = threadIdx.x;
    const int w = tid >> 6, lane = tid & 63;
    const int bid = (int)blockIdx.x;
    // XCD swizzle: 768 blocks = 96/XCD; 4 m-panels (2 MB A) resident per L2,
    // m varies fastest so concurrent blocks share B-panels.
    const int xcd = bid & 7, l = bid >> 3;
    const int m0 = (xcd * 4 + (l & 3)) * 256;
    const int n0 = (l >> 2) * 128;
    const int wrow = w >> 1, wcol = w & 1;
    const int l15 = lane & 15, l4 = lane >> 4;
    // staging lane constants: linear deposit pos (row=lane>>2, chunk=lane&3);
    // global chunk = chunk ^ swz(row), swz(row)=(row>>1)&3 = (lane>>3)&3.
    const int srow = lane >> 2;
    const int sg = ((lane & 3) ^ ((lane >> 3) & 3)) * 8;
    const unsigned short* gA0 = xb + (size_t)(m0 + w * 32 + srow) * 1024 + sg;
    const unsigned short* gA1 = gA0 + 16 * 1024;
    const unsigned short* gB0 = wt + (size_t)(n0 + w * 16 + srow) * 1024 + sg;
    unsigned short* lA = As + w * 1024;          // wave's 32 A-rows
    unsigned short* lB = Bs + w * 512;           // wave's 16 B-rows
    // swizzled read offsets
    const int swz = (l15 >> 1) & 3;
    const int ch8 = (l4 ^ swz) * 8;
    int aoff[4], boff[4];
    #pragma unroll
    for (int i = 0; i < 4; ++i) {
        aoff[i] = (wrow * 64 + i * 16 + l15) * 32 + ch8;
        boff[i] = (wcol * 64 + i * 16 + l15) * 32 + ch8;
    }
    f32x4 acc[4][4] = {};

    auto stage = [&](int tt, int sb) {
        const int ko = tt * 32;
        load_lds16(gA0 + ko, lA + sb * QK_ASTR);
        load_lds16(gA1 + ko, lA + sb * QK_ASTR + 512);
        load_lds16(gB0 + ko, lB + sb * QK_BSTR);
    };
    stage(0, 0); stage(1, 1); stage(2, 2);
    int sbuf = 3, cbuf = 0;
    for (int t = 0; t < 32; ++t) {
        if (t <= 28) {
            stage(t + 3, sbuf);
            sbuf = (sbuf == 4) ? 0 : sbuf + 1;
        }
        if (t <= 28)      asm volatile("s_waitcnt vmcnt(9)" ::: "memory");
        else if (t == 29) asm volatile("s_waitcnt vmcnt(6)" ::: "memory");
        else if (t == 30) asm volatile("s_waitcnt vmcnt(3)" ::: "memory");
        else              asm volatile("s_waitcnt vmcnt(0)" ::: "memory");
        __builtin_amdgcn_s_barrier();
        asm volatile("" ::: "memory");   // no LDS-read hoist above the barrier
        const unsigned short* Ab = As + cbuf * QK_ASTR;
        const unsigned short* Bb = Bs + cbuf * QK_BSTR;
        cbuf = (cbuf == 4) ? 0 : cbuf + 1;
        bf16x8 af[4], bfr[4];
        #pragma unroll
        for (int i = 0; i < 4; ++i) {
            af[i]  = *(const bf16x8*)&Ab[aoff[i]];
            bfr[i] = *(const bf16x8*)&Bb[boff[i]];
        }
        __builtin_amdgcn_s_setprio(1);
        #pragma unroll
        for (int mi = 0; mi < 4; ++mi)
            #pragma unroll
            for (int ni = 0; ni < 4; ++ni)
                acc[mi][ni] = __builtin_amdgcn_mfma_f32_16x16x32_bf16(af[mi], bfr[ni], acc[mi][ni], 0, 0, 0);
        __builtin_amdgcn_s_setprio(0);
    }
    #pragma unroll
    for (int mi = 0; mi < 4; ++mi) {
        #pragma unroll
        for (int ni = 0; ni < 4; ++ni) {
            const int col = n0 + wcol * 64 + ni * 16 + l15;
            const float bv = bias[col];
            const int part = col >> 10;
            const int cidx = col & 1023;
            const int h = cidx >> 7, d = cidx & 127;
            unsigned short* dst = (part == 0) ? qb : ((part == 1) ? kb : vb);
            #pragma unroll
            for (int r = 0; r < 4; ++r) {
                const int row = m0 + wrow * 64 + mi * 16 + l4 * 4 + r;
                const int b = row >> 10, s = row & 1023;
                dst[((size_t)(b * 8 + h) * 1024 + s) * 128 + d] = f2bf_rne(acc[mi][ni][r] + bv);
            }
        }
    }
}

// ---------------- flash attention (R5-exact, post-timing verified) ----------------
__global__ __launch_bounds__(256, 2) void attn(
    const unsigned short* __restrict__ qb,
    const unsigned short* __restrict__ kb,
    const unsigned short* __restrict__ vt,
    const float* __restrict__ amask,
    unsigned short* __restrict__ ah,
    unsigned short* __restrict__ al) {
    __shared__ unsigned short Ks[2][64 * 128];   // 2 x 16 KB, [k-local][d], chunk^=(row&15)
    __shared__ unsigned short Vs[128 * 64];      // 16 KB, [d][s-local], chunk^=(row&7)
    __shared__ unsigned short P_lds[4][16 * 72]; // 9 KB wave-private
    const int tid = threadIdx.x;
    const int w = tid >> 6, lane = tid & 63;
    const int l15 = lane & 15, l4 = lane >> 4;
    const int bidx = (int)blockIdx.x;
    const int qt = 15 - (bidx >> 6);
    const int h = bidx & 7, b = (bidx >> 3) & 7;
    const int bh = b * H_ + h;
    const unsigned short* Q = qb + (size_t)bh * S_ * HD_;
    const unsigned short* Kg = kb + (size_t)bh * S_ * HD_;
    const unsigned short* Vg = vt + (size_t)bh * S_ * HD_;
    unsigned short* pl = P_lds[w];
    const float L2E = 1.44269504088896341f;
    const float SCL = 0.08838834764831845f * L2E;
    const float M2  = 8.0f;

    const int q0 = qt * 64;
    const int q0w = q0 + w * 16;
    bf16x8 qf[4];
    #pragma unroll
    for (int s = 0; s < 4; ++s)
        qf[s] = *(const bf16x8*)(Q + (size_t)(q0w + l15) * 128 + s * 32 + l4 * 8);
    float lsum[4] = {0.f, 0.f, 0.f, 0.f};
    f32x4 o[8] = {};
    const int limit = (q0 + 64 > PREFIX) ? (q0 + 64) : PREFIX;
    const int nkt = (limit + 63) >> 6;

    const int kr = lane >> 4;
    const int kc = lane & 15;
    const int vr = lane >> 3;
    const int vc = lane & 7;

    #pragma unroll
    for (int j = 0; j < 4; ++j) {
        const int rl = w * 16 + j * 4 + kr;
        const int g = kc ^ (j * 4 + kr);
        load_lds16(Kg + (size_t)rl * 128 + g * 8, &Ks[0][(w * 16 + j * 4) * 128]);
    }

    for (int kt = 0; kt < nkt; ++kt) {
        const int kbase = kt * 64;
        const int cur = kt & 1;
        __syncthreads();
        if (kt + 1 < nkt) {
            const int kb2 = (kt + 1) * 64;
            #pragma unroll
            for (int j = 0; j < 4; ++j) {
                const int rl = w * 16 + j * 4 + kr;
                const int g = kc ^ (j * 4 + kr);
                load_lds16(Kg + (size_t)(kb2 + rl) * 128 + g * 8, &Ks[cur ^ 1][(w * 16 + j * 4) * 128]);
            }
        }
        #pragma unroll
        for (int j = 0; j < 4; ++j) {
            const int rv = w * 32 + j * 8 + vr;
            const int g = vc ^ vr;
            load_lds16(Vg + (size_t)rv * 1024 + kbase + g * 8, &Vs[(w * 32 + j * 8) * 64]);
        }
        const bool full = (kbase + 64 <= PREFIX) || (q0w >= PREFIX && kbase + 64 <= q0w);
        #pragma unroll
        for (int t = 0; t < 4; ++t) {
            f32x4 sa = {};
            #pragma unroll
            for (int s = 0; s < 4; ++s) {
                bf16x8 kf = *(const bf16x8*)&Ks[cur][(t * 16 + l15) * 128 + (((s * 4 + l4) ^ l15) * 8)];
                sa = __builtin_amdgcn_mfma_f32_16x16x32_bf16(qf[s], kf, sa, 0, 0, 0);
            }
            const int kcol = kbase + t * 16 + l15;
            const float am = fmaf(amask[b * S_ + kcol], L2E, -M2);
            float p[4];
            if (full) {
                #pragma unroll
                for (int r = 0; r < 4; ++r) p[r] = exp2f(fmaf(sa[r], SCL, am));
            } else {
                #pragma unroll
                for (int r = 0; r < 4; ++r) {
                    const int row = q0w + l4 * 4 + r;
                    const bool keep = (row < PREFIX) ? (kcol < PREFIX) : (kcol <= row);
                    const float e = exp2f(fmaf(sa[r], SCL, am));
                    p[r] = keep ? e : 0.f;
                }
            }
            #pragma unroll
            for (int r = 0; r < 4; ++r) {
                lsum[r] += p[r];
                pl[(l4 * 4 + r) * 72 + t * 16 + l15] = f2bf_rne(p[r]);
            }
        }
        bf16x8 pf0 = *(const bf16x8*)&pl[l15 * 72 + l4 * 8];
        bf16x8 pf1 = *(const bf16x8*)&pl[l15 * 72 + 32 + l4 * 8];
        __syncthreads();
        #pragma unroll
        for (int n = 0; n < 8; ++n) {
            bf16x8 vf = *(const bf16x8*)&Vs[(n * 16 + l15) * 64 + ((l4 ^ (l15 & 7)) * 8)];
            o[n] = __builtin_amdgcn_mfma_f32_16x16x32_bf16(pf0, vf, o[n], 0, 0, 0);
        }
        #pragma unroll
        for (int n = 0; n < 8; ++n) {
            bf16x8 vf = *(const bf16x8*)&Vs[(n * 16 + l15) * 64 + ((((4 + l4) ^ (l15 & 7))) * 8)];
            o[n] = __builtin_amdgcn_mfma_f32_16x16x32_bf16(pf1, vf, o[n], 0, 0, 0);
        }
    }
    float inv_l[4];
    #pragma unroll
    for (int r = 0; r < 4; ++r) {
        float sm = lsum[r];
        sm += __shfl_xor(sm, 1);
        sm += __shfl_xor(sm, 2);
        sm += __shfl_xor(sm, 4);
        sm += __shfl_xor(sm, 8);
        inv_l[r] = 1.0f / sm;
    }
    #pragma unroll
    for (int n = 0; n < 8; ++n) {
        const int d = n * 16 + l15;
        #pragma unroll
        for (int r = 0; r < 4; ++r) {
            const int s = q0w + l4 * 4 + r;
            const float val = o[n][r] * inv_l[r];
            const size_t idx = ((size_t)b * 1024 + s) * 1024 + h * 128 + d;
            unsigned short hv = f2bf_rne(val);
            ah[idx] = hv;
            al[idx] = f2bf_rne(val - bf2f(hv));
        }
    }
}

// ---------------- proj GEMM (R7 pipelined core; K = 2048 = a_hi then a_lo) ----------
__global__ __launch_bounds__(512, 2) void gemm_proj(
    const unsigned short* __restrict__ ahp,
    const unsigned short* __restrict__ alp,
    const unsigned short* __restrict__ wh,
    const float* __restrict__ bias,
    float* __restrict__ out) {
    __shared__ unsigned short As[5 * QK_ASTR];
    __shared__ unsigned short Bs[5 * QK_BSTR];
    const int tid = threadIdx.x;
    const int w = tid >> 6, lane = tid & 63;
    const int bid = (int)blockIdx.x;
    const int xcd = bid & 7, l = bid >> 3;        // 256 blocks = 32/XCD = 4m x 8n
    const int m0 = (xcd * 4 + (l & 3)) * 256;
    const int n0 = (l >> 2) * 128;
    const int wrow = w >> 1, wcol = w & 1;
    const int l15 = lane & 15, l4 = lane >> 4;
    const int srow = lane >> 2;
    const int sg = ((lane & 3) ^ ((lane >> 3) & 3)) * 8;
    const size_t offA = (size_t)(m0 + w * 32 + srow) * 1024 + sg;
    const unsigned short* gAh = ahp + offA;
    const unsigned short* gAl = alp + offA;
    const unsigned short* gB0 = wh + (size_t)(n0 + w * 16 + srow) * 1024 + sg;
    unsigned short* lA = As + w * 1024;
    unsigned short* lB = Bs + w * 512;
    const int swz = (l15 >> 1) & 3;
    const int ch8 = (l4 ^ swz) * 8;
    int aoff[4], boff[4];
    #pragma unroll
    for (int i = 0; i < 4; ++i) {
        aoff[i] = (wrow * 64 + i * 16 + l15) * 32 + ch8;
        boff[i] = (wcol * 64 + i * 16 + l15) * 32 + ch8;
    }
    f32x4 acc[4][4] = {};

    auto stage = [&](int tt, int sb) {
        const int ko = (tt & 31) * 32;
        const unsigned short* a = (tt < 32 ? gAh : gAl) + ko;
        load_lds16(a, lA + sb * QK_ASTR);
        load_lds16(a + 16 * 1024, lA + sb * QK_ASTR + 512);
        load_lds16(gB0 + ko, lB + sb * QK_BSTR);
    };
    stage(0, 0); stage(1, 1); stage(2, 2);
    int sbuf = 3, cbuf = 0;
    for (int t = 0; t < 64; ++t) {
        if (t <= 60) {
            stage(t + 3, sbuf);
            sbuf = (sbuf == 4) ? 0 : sbuf + 1;
        }
        if (t <= 60)      asm volatile("s_waitcnt vmcnt(9)" ::: "memory");
        else if (t == 61) asm volatile("s_waitcnt vmcnt(6)" ::: "memory");
        else if (t == 62) asm volatile("s_waitcnt vmcnt(3)" ::: "memory");
        else              asm volatile("s_waitcnt vmcnt(0)" ::: "memory");
        __builtin_amdgcn_s_barrier();
        asm volatile("" ::: "memory");
        const unsigned short* Ab = As + cbuf * QK_ASTR;
        const unsigned short* Bb = Bs + cbuf * QK_BSTR;
        cbuf = (cbuf == 4) ? 0 : cbuf + 1;
        bf16x8 af[4], bfr[4];
        #pragma unroll
        for (int i = 0; i < 4; ++i) {
            af[i]  = *(const bf16x8*)&Ab[aoff[i]];
            bfr[i] = *(const bf16x8*)&Bb[boff[i]];
        }
        __builtin_amdgcn_s_setprio(1);
        #pragma unroll
        for (int mi = 0; mi < 4; ++mi)
            #pragma unroll
            for (int ni = 0; ni < 4; ++ni)
                acc[mi][ni] = __builtin_amdgcn_mfma_f32_16x16x32_bf16(af[mi], bfr[ni], acc[mi][ni], 0, 0, 0);
        __builtin_amdgcn_s_setprio(0);
    }
    #pragma unroll
    for (int mi = 0; mi < 4; ++mi) {
        #pragma unroll
        for (int ni = 0; ni < 4; ++ni) {
            const int col = n0 + wcol * 64 + ni * 16 + l15;
            const float bv = bias[col];
            #pragma unroll
            for (int r = 0; r < 4; ++r) {
                const int row = m0 + wrow * 64 + mi * 16 + l4 * 4 + r;
                out[(size_t)row * 1024 + col] = acc[mi][ni][r] + bv;
            }
        }
    }
}

// ---------------- launch ----------------
extern "C" void kernel_launch(void* const* d_in, const int* in_sizes, int n_in,
                              void* d_out, int out_size, void* d_ws, size_t ws_size,
                              hipStream_t stream) {
    const float* x      = (const float*)d_in[0];
    const float* amask  = (const float*)d_in[1];
    const float* W_attn = (const float*)d_in[2];
    const float* b_attn = (const float*)d_in[3];
    const float* W_proj = (const float*)d_in[4];
    const float* b_proj = (const float*)d_in[5];
    float* out = (float*)d_out;

    char* ws = (char*)d_ws;
    unsigned short* xb  = (unsigned short*)(ws);                 // 16 MB  x bf16 [8192][1024]
    unsigned short* wta = (unsigned short*)(ws + 16777216);      // 6 MB   W_attn^T bf16 [3072][1024]
    unsigned short* qb  = (unsigned short*)(ws + 23068672);      // 16 MB  Q [b,h,s,d]
    unsigned short* kb2 = (unsigned short*)(ws + 39845888);      // 16 MB  K [b,h,s,d]
    unsigned short* vb  = (unsigned short*)(ws + 56623104);      // 16 MB  V [b,h,s,d]
    unsigned short* vtb = (unsigned short*)(ws + 73400320);      // 16 MB  Vt [b,h,d,s]
    unsigned short* ahi = (unsigned short*)(ws + 90177536);      // 16 MB  a hi bf16 [8192][1024]
    unsigned short* alo = (unsigned short*)(ws + 106954752);     // 16 MB  a lo bf16
    unsigned short* wph = (unsigned short*)(ws + 123731968);     // 2 MB   W_proj^T hi

    cvt_bf16<<<8192, 256, 0, stream>>>(x, xb, (B_ * S_ * D_) / 4);
    transpose_cvt<<<dim3(N3_ / 32, D_ / 32), dim3(32, 8), 0, stream>>>(W_attn, wta, D_, N3_);
    transpose_cvt<<<dim3(D_ / 32, D_ / 32), dim3(32, 8), 0, stream>>>(W_proj, wph, D_, D_);
    gemm_qkv<<<dim3(768), 512, 0, stream>>>(xb, wta, b_attn, qb, kb2, vb);
    transpose_v<<<dim3(HD_ / 32, S_ / 32, B_ * H_), dim3(32, 8), 0, stream>>>(vb, vtb);
    attn<<<dim3(1024), 256, 0, stream>>>(qb, kb2, vtb, amask, ahi, alo);
    gemm_proj<<<dim3(256), 512, 0, stream>>>(ahi, alo, wph, b_proj, out);
}